// Round 9
// baseline (187.432 us; speedup 1.0000x reference)
//
#include <hip/hip_runtime.h>
#include <math.h>

#define B_ 8
#define C_ 64
#define K_ 32
#define HW_ 16384
#define NCHUNKOUT_ 64        // one partial slab per corr block (256 n each)
#define TILE_ 256            // fusion px tile
#define NEG_SLOPE_ 0.1f

// ws layout:
//   [0, 8MB)          float partial[B_][NCHUNKOUT_][C_][C_]
//   [8MB, 8MB+64KB)   int   idxb[B_][C_][K_]

__device__ __forceinline__ void gl_lds16(const float* g, float* l) {
    // async global->LDS, 16 B/lane; LDS dest = uniform base + lane*16 (linear)
    __builtin_amdgcn_global_load_lds(
        (const __attribute__((address_space(1))) void*)g,
        (__attribute__((address_space(3))) void*)l,
        16, 0, 0);
}

// corr v6: m97-style staging. Block = 512 t (8 waves), 256 n per block in
// 2 iters of 128 n. LDS [64][128] per array, XOR-swizzled via pre-swizzled
// GLOBAL source (phys_col = lin_col ^ ((row&7)*4)) so the linear
// global_load_lds dest yields a conflict-free layout for the strided
// 8x8-register-tile reads (bank-quad = (col/4 ^ row&7) % 8 -> all distinct).
__global__ __launch_bounds__(512, 4) void corr_partial_kernel(
    const float* __restrict__ LR, const float* __restrict__ HR,
    float* __restrict__ partial)
{
    __shared__ float smem[16384];        // 64 KB: lrS [64][128] + hrS [64][128]
    float* lrS = smem;
    float* hrS = smem + 8192;

    const int bid = blockIdx.x;          // 512 = B * 64
    const int b = bid >> 6;
    const int q = bid & 63;
    const int t = threadIdx.x;
    const int wv = t >> 6;               // 0..7
    const int lane = t & 63;
    const int cq = lane >> 3;            // 0..7
    const int dq = lane & 7;             // 0..7

    float acc[8][8] = {};

    #pragma unroll 1
    for (int it = 0; it < 2; ++it) {
        const int n0 = q * 256 + it * 128;
        if (it) __syncthreads();         // WAR: prev compute done before restage

        // stage: wave wv owns rows [wv*8, wv*8+8) of both arrays.
        // Each gl_lds16 instr writes 1 KB = 2 rows; lane -> row r0+(lane>>5),
        // phys col (lane&31)*4; global col = phys ^ ((row&7)*4).
        #pragma unroll
        for (int s = 0; s < 4; ++s) {
            const int r0 = wv * 8 + s * 2;
            const int row = r0 + (lane >> 5);
            const int cl = (((lane & 31) * 4) ^ ((row & 7) * 4));
            const size_t goff = (size_t)(b * C_ + row) * HW_ + n0 + cl;
            gl_lds16(&LR[goff], &lrS[r0 * 128]);
            gl_lds16(&HR[goff], &hrS[r0 * 128]);
        }
        __syncthreads();                 // RAW: drains vmcnt before compute

        // wave wv computes over its n-cols [wv*16, wv*16+16)
        #pragma unroll
        for (int nq = 0; nq < 4; ++nq) {
            const int col = wv * 16 + nq * 4;
            const int cxl = col ^ (cq * 4);
            const int cxh = col ^ (dq * 4);
            float4 lv[8];
            #pragma unroll
            for (int i = 0; i < 8; ++i)
                lv[i] = *reinterpret_cast<const float4*>(&lrS[(cq + 8 * i) * 128 + cxl]);
            #pragma unroll
            for (int j = 0; j < 8; ++j) {
                const float4 hv = *reinterpret_cast<const float4*>(&hrS[(dq + 8 * j) * 128 + cxh]);
                #pragma unroll
                for (int i = 0; i < 8; ++i) {
                    acc[i][j] = fmaf(lv[i].x, hv.x, acc[i][j]);
                    acc[i][j] = fmaf(lv[i].y, hv.y, acc[i][j]);
                    acc[i][j] = fmaf(lv[i].z, hv.z, acc[i][j]);
                    acc[i][j] = fmaf(lv[i].w, hv.w, acc[i][j]);
                }
            }
        }
    }

    // cross-wave reduction, b128, 2 phases of 32 output-positions.
    // slot sl -> (i = ph*4 + (sl>>1), j0 = (sl&1)*4); red[w][sl][lane][4].
    float* red = smem;                   // reuse 64 KB
    float* P = partial + (size_t)bid * (C_ * C_);
    #pragma unroll 1
    for (int ph = 0; ph < 2; ++ph) {
        __syncthreads();                 // prior smem use complete
        #pragma unroll
        for (int sl = 0; sl < 8; ++sl) {
            const int i = ph * 4 + (sl >> 1);
            const int j0 = (sl & 1) * 4;
            *reinterpret_cast<float4*>(&red[((wv * 8 + sl) * 64 + lane) * 4]) =
                make_float4(acc[i][j0], acc[i][j0 + 1], acc[i][j0 + 2], acc[i][j0 + 3]);
        }
        __syncthreads();
        {
            const int sl = t >> 6;       // this thread reduces slot sl at its lane
            float4 s = make_float4(0.f, 0.f, 0.f, 0.f);
            #pragma unroll
            for (int w = 0; w < 8; ++w) {   // fixed order -> deterministic
                const float4 v = *reinterpret_cast<const float4*>(
                    &red[((w * 8 + sl) * 64 + lane) * 4]);
                s.x += v.x; s.y += v.y; s.z += v.z; s.w += v.w;
            }
            const int i = ph * 4 + (sl >> 1);
            const int j0 = (sl & 1) * 4;
            const int row = (lane >> 3) + 8 * i;
            const int colb = (lane & 7) + 8 * j0;
            P[row * C_ + colb]      = s.x;
            P[row * C_ + colb + 8]  = s.y;
            P[row * C_ + colb + 16] = s.z;
            P[row * C_ + colb + 24] = s.w;
        }
    }
}

// Reduce partials (f64, deterministic), rank channels per (b,c) like lax.top_k
// (stable descending), emit top-K channel indices.  (round-6 version)
__global__ __launch_bounds__(64) void rank_kernel(
    const float* __restrict__ partial, int* __restrict__ idxb)
{
    __shared__ double vals[C_];
    const int blk = blockIdx.x;     // b*64 + c
    const int b = blk >> 6;
    const int c = blk & 63;
    const int d = threadIdx.x;

    double acc = 0.0;
    for (int k = 0; k < NCHUNKOUT_; ++k)
        acc += (double)partial[(size_t)(b * NCHUNKOUT_ + k) * (C_ * C_) + c * C_ + d];
    vals[d] = acc;
    __syncthreads();

    int r = 0;
    for (int jj = 0; jj < C_; ++jj) {
        const double vj = vals[jj];
        r += (int)((vj > acc) || (vj == acc && jj < d));   // stable descending rank
    }
    if (r < K_) idxb[blk * K_ + r] = d;
}

// Gather fusion (round-8 version, unchanged): stage HR[64][256] px-slab in
// LDS; 8 waves x 8 c each; gather via ds_read_b128 (1 KB/wave-instr).
__global__ __launch_bounds__(512, 4) void fusion_gather_kernel(
    const float* __restrict__ HR, const float* __restrict__ LR,
    const int* __restrict__ idxb,
    const float* __restrict__ w1, const float* __restrict__ b1,
    const float* __restrict__ w2, const float* __restrict__ b2,
    float* __restrict__ out)
{
    __shared__ float hrS[C_][TILE_];   // 64 KB

    const int t = threadIdx.x;
    const int bid = blockIdx.x;        // 512 = B * (HW/TILE)
    const int b = bid >> 6;
    const int px0 = (bid & 63) * TILE_;

    const float* HRb = HR + (size_t)b * C_ * HW_;
    #pragma unroll
    for (int i = 0; i < 8; ++i) {
        const int f = i * 512 + t;
        const int c = f >> 6;
        const int qq = f & 63;
        *reinterpret_cast<float4*>(&hrS[c][qq * 4]) =
            *reinterpret_cast<const float4*>(&HRb[(size_t)c * HW_ + px0 + qq * 4]);
    }
    __syncthreads();

    const int wv = t >> 6;             // wave id -> c-octant
    const int lane = t & 63;
    const int p4 = lane * 4;           // this lane's 4 px within the tile

    const int* idxc = idxb + b * C_ * K_;
    const float w10 = w1[0];
    const float b1v = b1[0], w2v = w2[0], b2v = b2[0];

    #pragma unroll 1
    for (int ci = 0; ci < 8; ++ci) {
        const int c = wv * 8 + ci;
        const float4 l4 = *reinterpret_cast<const float4*>(
            &LR[(size_t)(b * C_ + c) * HW_ + px0 + p4]);         // issue early
        float acc[4] = {0.f, 0.f, 0.f, 0.f};
        float mx[4]  = {-1e30f, -1e30f, -1e30f, -1e30f};
        #pragma unroll
        for (int k = 0; k < K_; ++k) {
            const int d = idxc[c * K_ + k];          // uniform -> s_load
            const float4 h = *reinterpret_cast<const float4*>(&hrS[d][p4]);
            const float wk = w1[k + 1];              // uniform -> SGPR
            acc[0] = fmaf(h.x, wk, acc[0]);
            acc[1] = fmaf(h.y, wk, acc[1]);
            acc[2] = fmaf(h.z, wk, acc[2]);
            acc[3] = fmaf(h.w, wk, acc[3]);
            mx[0] = fmaxf(mx[0], h.x);
            mx[1] = fmaxf(mx[1], h.y);
            mx[2] = fmaxf(mx[2], h.z);
            mx[3] = fmaxf(mx[3], h.w);
        }
        const float l[4] = {l4.x, l4.y, l4.z, l4.w};
        float o[4];
        #pragma unroll
        for (int p = 0; p < 4; ++p) {
            float f = fmaf(w10, l[p], acc[p]) + b1v;
            f = f >= 0.f ? f : NEG_SLOPE_ * f;
            f = fmaf(w2v, f, b2v);
            const float s = 1.f / (1.f + __expf(-mx[p]));
            o[p] = f * (1.f + s);
        }
        *reinterpret_cast<float4*>(&out[(size_t)(b * C_ + c) * HW_ + px0 + p4]) =
            make_float4(o[0], o[1], o[2], o[3]);
    }
}

extern "C" void kernel_launch(void* const* d_in, const int* in_sizes, int n_in,
                              void* d_out, int out_size, void* d_ws, size_t ws_size,
                              hipStream_t stream)
{
    const float* HR = (const float*)d_in[0];
    const float* LR = (const float*)d_in[1];
    const float* w1 = (const float*)d_in[2];
    const float* b1 = (const float*)d_in[3];
    const float* w2 = (const float*)d_in[4];
    const float* b2 = (const float*)d_in[5];
    float* out = (float*)d_out;

    float* partial = (float*)d_ws;
    int* idxb = (int*)((char*)d_ws + (size_t)B_ * NCHUNKOUT_ * C_ * C_ * sizeof(float));

    corr_partial_kernel<<<B_ * 64, 512, 0, stream>>>(LR, HR, partial);
    rank_kernel<<<B_ * C_, 64, 0, stream>>>(partial, idxb);
    fusion_gather_kernel<<<B_ * (HW_ / TILE_), 512, 0, stream>>>(HR, LR, idxb, w1, b1, w2, b2, out);
}

// Round 10
// 73.534 us; speedup vs baseline: 2.5489x; 2.5489x over previous
//
#include <hip/hip_runtime.h>
#include <math.h>

#define B_ 8
#define C_ 64
#define K_ 32
#define HW_ 16384
#define NCHUNKOUT_ 64        // one partial slab per corr block (256 n each)
#define TILE_ 256            // fusion px tile
#define NEG_SLOPE_ 0.1f

// ws layout:
//   [0, 8MB)          float partial[B_][NCHUNKOUT_][C_][C_]
//   [8MB, 8MB+64KB)   int   idxb[B_][C_][K_]

__device__ __forceinline__ void gl_lds16(const float* g, float* l) {
    // async global->LDS, 16 B/lane; LDS dest = wave-uniform base + lane*16
    __builtin_amdgcn_global_load_lds(
        (const __attribute__((address_space(1))) void*)g,
        (__attribute__((address_space(3))) void*)l,
        16, 0, 0);
}

// corr v7: 256 threads (4 waves), __launch_bounds__(256,2) -> 2 blocks/CU,
// 2 waves/SIMD, VGPR cap 256 (no spill; needs ~120).
// gl_lds16 staging of [64][128] per array, XOR-swizzled via the GLOBAL source
// address (phys_col = lin_col ^ ((row&7)*4)); compute reads apply the same
// XOR -> per-instr bank-quad = (col/4 ^ row&7)%8, 8 distinct quads x 8-lane
// broadcast = conflict-free.
__global__ __launch_bounds__(256, 2) void corr_partial_kernel(
    const float* __restrict__ LR, const float* __restrict__ HR,
    float* __restrict__ partial)
{
    __shared__ float smem[16384];        // 64 KB: lrS [64][128] + hrS [64][128]
    float* lrS = smem;
    float* hrS = smem + 8192;

    const int bid = blockIdx.x;          // 512 = B * 64
    const int b = bid >> 6;
    const int q = bid & 63;
    const int t = threadIdx.x;
    const int wv = t >> 6;               // 0..3
    const int lane = t & 63;
    const int cq = lane >> 3;            // 0..7
    const int dq = lane & 7;             // 0..7

    float acc[8][8] = {};

    #pragma unroll 1
    for (int it = 0; it < 2; ++it) {
        const int n0 = q * 256 + it * 128;
        if (it) __syncthreads();         // WAR: prev compute done before restage

        // stage: wave wv owns rows [wv*16, wv*16+16) of both arrays.
        // Each gl_lds16 writes 1 KB = 2 rows; lane -> row r0+(lane>>5),
        // phys col (lane&31)*4; global col = phys ^ ((row&7)*4).
        #pragma unroll
        for (int s = 0; s < 8; ++s) {
            const int r0 = wv * 16 + s * 2;
            const int row = r0 + (lane >> 5);
            const int cl = (((lane & 31) * 4) ^ ((row & 7) * 4));
            const size_t goff = (size_t)(b * C_ + row) * HW_ + n0 + cl;
            gl_lds16(&LR[goff], &lrS[r0 * 128]);
            gl_lds16(&HR[goff], &hrS[r0 * 128]);
        }
        __syncthreads();                 // RAW: drains vmcnt before compute

        // wave wv computes over its n-cols [wv*32, wv*32+32)
        #pragma unroll
        for (int nq = 0; nq < 8; ++nq) {
            const int col = wv * 32 + nq * 4;
            const int cxl = col ^ (cq * 4);
            const int cxh = col ^ (dq * 4);
            float4 lv[8];
            #pragma unroll
            for (int i = 0; i < 8; ++i)
                lv[i] = *reinterpret_cast<const float4*>(&lrS[(cq + 8 * i) * 128 + cxl]);
            #pragma unroll
            for (int j = 0; j < 8; ++j) {
                const float4 hv = *reinterpret_cast<const float4*>(&hrS[(dq + 8 * j) * 128 + cxh]);
                #pragma unroll
                for (int i = 0; i < 8; ++i) {
                    acc[i][j] = fmaf(lv[i].x, hv.x, acc[i][j]);
                    acc[i][j] = fmaf(lv[i].y, hv.y, acc[i][j]);
                    acc[i][j] = fmaf(lv[i].z, hv.z, acc[i][j]);
                    acc[i][j] = fmaf(lv[i].w, hv.w, acc[i][j]);
                }
            }
        }
    }

    // cross-wave reduction, single phase: red[w][sl][lane][4] = 64 KB.
    // slot sl (0..15) -> (i = sl>>1, j0 = (sl&1)*4).
    __syncthreads();
    float* red = smem;
    #pragma unroll
    for (int sl = 0; sl < 16; ++sl) {
        const int i = sl >> 1;
        const int j0 = (sl & 1) * 4;
        *reinterpret_cast<float4*>(&red[((wv * 16 + sl) * 64 + lane) * 4]) =
            make_float4(acc[i][j0], acc[i][j0 + 1], acc[i][j0 + 2], acc[i][j0 + 3]);
    }
    __syncthreads();

    float* P = partial + (size_t)bid * (C_ * C_);
    #pragma unroll
    for (int pp = 0; pp < 4; ++pp) {
        const int sl = wv * 4 + pp;      // this wave reduces slots [wv*4, wv*4+4)
        float4 s = make_float4(0.f, 0.f, 0.f, 0.f);
        #pragma unroll
        for (int w = 0; w < 4; ++w) {    // fixed order -> deterministic
            const float4 v = *reinterpret_cast<const float4*>(
                &red[((w * 16 + sl) * 64 + lane) * 4]);
            s.x += v.x; s.y += v.y; s.z += v.z; s.w += v.w;
        }
        const int i = sl >> 1;
        const int j0 = (sl & 1) * 4;
        const int row = (lane >> 3) + 8 * i;
        const int colb = (lane & 7) + 8 * j0;
        P[row * C_ + colb]      = s.x;
        P[row * C_ + colb + 8]  = s.y;
        P[row * C_ + colb + 16] = s.z;
        P[row * C_ + colb + 24] = s.w;
    }
}

// Reduce partials (f64, deterministic), rank channels per (b,c) like lax.top_k
// (stable descending), emit top-K channel indices.
__global__ __launch_bounds__(64) void rank_kernel(
    const float* __restrict__ partial, int* __restrict__ idxb)
{
    __shared__ double vals[C_];
    const int blk = blockIdx.x;     // b*64 + c
    const int b = blk >> 6;
    const int c = blk & 63;
    const int d = threadIdx.x;

    double acc = 0.0;
    for (int k = 0; k < NCHUNKOUT_; ++k)
        acc += (double)partial[(size_t)(b * NCHUNKOUT_ + k) * (C_ * C_) + c * C_ + d];
    vals[d] = acc;
    __syncthreads();

    int r = 0;
    for (int jj = 0; jj < C_; ++jj) {
        const double vj = vals[jj];
        r += (int)((vj > acc) || (vj == acc && jj < d));   // stable descending rank
    }
    if (r < K_) idxb[blk * K_ + r] = d;
}

// Gather fusion: stage HR[64][256] px-slab in LDS; 8 waves x 8 c each;
// gather via ds_read_b128 (1 KB/wave-instr). (512,2): VGPR cap 128 (needs ~88);
// LDS 64KB already limits to 2 blocks/CU.
__global__ __launch_bounds__(512, 2) void fusion_gather_kernel(
    const float* __restrict__ HR, const float* __restrict__ LR,
    const int* __restrict__ idxb,
    const float* __restrict__ w1, const float* __restrict__ b1,
    const float* __restrict__ w2, const float* __restrict__ b2,
    float* __restrict__ out)
{
    __shared__ float hrS[C_][TILE_];   // 64 KB

    const int t = threadIdx.x;
    const int bid = blockIdx.x;        // 512 = B * (HW/TILE)
    const int b = bid >> 6;
    const int px0 = (bid & 63) * TILE_;

    const float* HRb = HR + (size_t)b * C_ * HW_;
    #pragma unroll
    for (int i = 0; i < 8; ++i) {
        const int f = i * 512 + t;
        const int c = f >> 6;
        const int qq = f & 63;
        *reinterpret_cast<float4*>(&hrS[c][qq * 4]) =
            *reinterpret_cast<const float4*>(&HRb[(size_t)c * HW_ + px0 + qq * 4]);
    }
    __syncthreads();

    const int wv = t >> 6;             // wave id -> c-octant
    const int lane = t & 63;
    const int p4 = lane * 4;           // this lane's 4 px within the tile

    const int* idxc = idxb + b * C_ * K_;
    const float w10 = w1[0];
    const float b1v = b1[0], w2v = w2[0], b2v = b2[0];

    #pragma unroll 1
    for (int ci = 0; ci < 8; ++ci) {
        const int c = wv * 8 + ci;
        const float4 l4 = *reinterpret_cast<const float4*>(
            &LR[(size_t)(b * C_ + c) * HW_ + px0 + p4]);         // issue early
        float acc[4] = {0.f, 0.f, 0.f, 0.f};
        float mx[4]  = {-1e30f, -1e30f, -1e30f, -1e30f};
        #pragma unroll
        for (int k = 0; k < K_; ++k) {
            const int d = idxc[c * K_ + k];          // uniform -> s_load
            const float4 h = *reinterpret_cast<const float4*>(&hrS[d][p4]);
            const float wk = w1[k + 1];              // uniform -> SGPR
            acc[0] = fmaf(h.x, wk, acc[0]);
            acc[1] = fmaf(h.y, wk, acc[1]);
            acc[2] = fmaf(h.z, wk, acc[2]);
            acc[3] = fmaf(h.w, wk, acc[3]);
            mx[0] = fmaxf(mx[0], h.x);
            mx[1] = fmaxf(mx[1], h.y);
            mx[2] = fmaxf(mx[2], h.z);
            mx[3] = fmaxf(mx[3], h.w);
        }
        const float l[4] = {l4.x, l4.y, l4.z, l4.w};
        float o[4];
        #pragma unroll
        for (int p = 0; p < 4; ++p) {
            float f = fmaf(w10, l[p], acc[p]) + b1v;
            f = f >= 0.f ? f : NEG_SLOPE_ * f;
            f = fmaf(w2v, f, b2v);
            const float s = 1.f / (1.f + __expf(-mx[p]));
            o[p] = f * (1.f + s);
        }
        *reinterpret_cast<float4*>(&out[(size_t)(b * C_ + c) * HW_ + px0 + p4]) =
            make_float4(o[0], o[1], o[2], o[3]);
    }
}

extern "C" void kernel_launch(void* const* d_in, const int* in_sizes, int n_in,
                              void* d_out, int out_size, void* d_ws, size_t ws_size,
                              hipStream_t stream)
{
    const float* HR = (const float*)d_in[0];
    const float* LR = (const float*)d_in[1];
    const float* w1 = (const float*)d_in[2];
    const float* b1 = (const float*)d_in[3];
    const float* w2 = (const float*)d_in[4];
    const float* b2 = (const float*)d_in[5];
    float* out = (float*)d_out;

    float* partial = (float*)d_ws;
    int* idxb = (int*)((char*)d_ws + (size_t)B_ * NCHUNKOUT_ * C_ * C_ * sizeof(float));

    corr_partial_kernel<<<B_ * 64, 256, 0, stream>>>(LR, HR, partial);
    rank_kernel<<<B_ * C_, 64, 0, stream>>>(partial, idxb);
    fusion_gather_kernel<<<B_ * (HW_ / TILE_), 512, 0, stream>>>(HR, LR, idxb, w1, b1, w2, b2, out);
}